// Round 1
// baseline (1251.412 us; speedup 1.0000x reference)
//
#include <hip/hip_runtime.h>
#include <math.h>

// Problem constants
#define BT_   1024   // B*T
#define EPS_  2.220446049250313e-16f

__device__ __forceinline__ float gelu_exact(float x) {
    return 0.5f * x * (1.0f + erff(x * 0.70710678118654752f));
}

// ---------------------------------------------------------------------------
// K0: reorder conv weights OIHW -> [k = kh*kW*C + kw*C + c][o]
// ---------------------------------------------------------------------------
__global__ __launch_bounds__(256) void k_reorder(
        const float* __restrict__ w1, const float* __restrict__ w2,
        float* __restrict__ w1r, float* __restrict__ w2r) {
    int i = blockIdx.x * 256 + threadIdx.x;
    if (i < 16384) {                 // conv1: (64,16,4,4) -> (256,64)
        int o = i & 63, r = i >> 6;
        int c = r & 15; r >>= 4;
        int kw = r & 3, kh = r >> 2;
        w1r[i] = w1[((o * 16 + c) * 4 + kh) * 4 + kw];
    }
    if (i < 262144) {                // conv2: (256,64,4,4) -> (1024,256)
        int o = i & 255, r = i >> 8;
        int c = r & 63; r >>= 6;
        int kw = r & 3, kh = r >> 2;
        w2r[i] = w2[((o * 64 + c) * 4 + kh) * 4 + kw];
    }
}

// ---------------------------------------------------------------------------
// K1: conv1 (stride4 k4, patch-GEMM 256x64) + LN(64) + gelu
// grid = BT*16 (bt, oh); block 256.
// thread tile: 4 couts x 1 pixel. cg = lane&15 (cout=cg*4+j), px = wave*4+(lane>>4)
// ---------------------------------------------------------------------------
__global__ __launch_bounds__(256) void k_conv1(
        const float* __restrict__ x, const float* __restrict__ w1r,
        const float* __restrict__ cb, const float* __restrict__ g,
        const float* __restrict__ bb, float* __restrict__ out) {
    __shared__ __align__(16) float xin[4096];      // 4 input rows (4,64,16)
    __shared__ __align__(16) float wl[128 * 64];   // K-half x 64 couts

    int blk = blockIdx.x;
    int bt = blk >> 4, oh = blk & 15;
    int tid = threadIdx.x;
    int lane = tid & 63, wave = tid >> 6;
    int cg = lane & 15;
    int px = wave * 4 + (lane >> 4);   // = ow, 0..15

    const float* xsrc = x + (size_t)bt * 65536 + (size_t)oh * 4096;
    for (int i = tid; i < 4096; i += 256) xin[i] = xsrc[i];

    float acc[4] = {0.f, 0.f, 0.f, 0.f};

    for (int kh2 = 0; kh2 < 2; ++kh2) {
        __syncthreads();
        for (int i = tid; i < 8192; i += 256) wl[i] = w1r[kh2 * 8192 + i];
        __syncthreads();
        #pragma unroll 4
        for (int kk = 0; kk < 128; kk += 4) {
            int k = kh2 * 128 + kk;            // k = kh*64 + kw*16 + c
            int kh = k >> 6;
            int inner = k & 63;                // kw*16 + c (c quad-aligned)
            float4 x4 = *(const float4*)&xin[kh * 1024 + px * 64 + inner];
            const float* wbase = &wl[kk * 64 + cg * 4];
            float4 w0 = *(const float4*)(wbase);
            float4 w1_ = *(const float4*)(wbase + 64);
            float4 w2_ = *(const float4*)(wbase + 128);
            float4 w3_ = *(const float4*)(wbase + 192);
            acc[0] += x4.x * w0.x + x4.y * w1_.x + x4.z * w2_.x + x4.w * w3_.x;
            acc[1] += x4.x * w0.y + x4.y * w1_.y + x4.z * w2_.y + x4.w * w3_.y;
            acc[2] += x4.x * w0.z + x4.y * w1_.z + x4.z * w2_.z + x4.w * w3_.z;
            acc[3] += x4.x * w0.w + x4.y * w1_.w + x4.z * w2_.w + x4.w * w3_.w;
        }
    }

    // conv bias (before LN stats)
    float4 cbv = *(const float4*)&cb[cg * 4];
    acc[0] += cbv.x; acc[1] += cbv.y; acc[2] += cbv.z; acc[3] += cbv.w;

    // LN over 64 channels: reduce across the 16 cg lanes (xor bits 0..3)
    float s = acc[0] + acc[1] + acc[2] + acc[3];
    float ss = acc[0]*acc[0] + acc[1]*acc[1] + acc[2]*acc[2] + acc[3]*acc[3];
    #pragma unroll
    for (int d = 1; d < 16; d <<= 1) {
        s  += __shfl_xor(s, d, 64);
        ss += __shfl_xor(ss, d, 64);
    }
    float m = s * (1.f / 64.f);
    float var = ss * (1.f / 64.f) - m * m;
    float rs = rsqrtf(var + 1e-5f);

    float4 gv = *(const float4*)&g[cg * 4];
    float4 bv = *(const float4*)&bb[cg * 4];
    float4 y;
    y.x = gelu_exact((acc[0] - m) * rs * gv.x + bv.x);
    y.y = gelu_exact((acc[1] - m) * rs * gv.y + bv.y);
    y.z = gelu_exact((acc[2] - m) * rs * gv.z + bv.z);
    y.w = gelu_exact((acc[3] - m) * rs * gv.w + bv.w);
    *(float4*)&out[(((size_t)bt * 16 + oh) * 16 + px) * 64 + cg * 4] = y;
}

// ---------------------------------------------------------------------------
// K2: conv2 (patch-GEMM 1024x256) + LN(256) + gelu
// grid = BT (one full (16,16,64) image in LDS); block 256.
// thread tile: 4 couts x 4 pixels. o = wave*64+(lane&15)*4, px = (lane>>4)*4+i
// weights streamed from global (L2-resident, 1 MB).
// ---------------------------------------------------------------------------
__global__ __launch_bounds__(256) void k_conv2(
        const float* __restrict__ s1, const float* __restrict__ w2r,
        const float* __restrict__ cb, const float* __restrict__ g,
        const float* __restrict__ bb, float* __restrict__ out) {
    __shared__ __align__(16) float xin[16384];   // 64KB: whole image (16,16,64)

    int bt = blockIdx.x;
    int tid = threadIdx.x, lane = tid & 63, wave = tid >> 6;
    const float* src = s1 + (size_t)bt * 16384;
    for (int i = tid; i < 16384; i += 256) xin[i] = src[i];
    __syncthreads();

    int og = wave * 64 + (lane & 15) * 4;   // couts og..og+3
    int pxb = (lane >> 4) * 4;              // pixels pxb..pxb+3

    float acc[4][4];
    #pragma unroll
    for (int i = 0; i < 4; ++i)
        #pragma unroll
        for (int j = 0; j < 4; ++j) acc[i][j] = 0.f;

    #pragma unroll 2
    for (int k = 0; k < 1024; k += 4) {     // k = kh*256 + kw*64 + c
        int kh = k >> 8;
        int klow = k & 255;                 // kw*64 + c, quad-aligned
        float4 wq0 = *(const float4*)&w2r[(size_t)(k + 0) * 256 + og];
        float4 wq1 = *(const float4*)&w2r[(size_t)(k + 1) * 256 + og];
        float4 wq2 = *(const float4*)&w2r[(size_t)(k + 2) * 256 + og];
        float4 wq3 = *(const float4*)&w2r[(size_t)(k + 3) * 256 + og];
        int koff = kh * 1024 + klow;
        #pragma unroll
        for (int i = 0; i < 4; ++i) {
            int px = pxb + i;
            int ohl = px >> 2, ow = px & 3;
            float4 xa = *(const float4*)&xin[ohl * 4096 + ow * 256 + koff];
            acc[i][0] += xa.x * wq0.x + xa.y * wq1.x + xa.z * wq2.x + xa.w * wq3.x;
            acc[i][1] += xa.x * wq0.y + xa.y * wq1.y + xa.z * wq2.y + xa.w * wq3.y;
            acc[i][2] += xa.x * wq0.z + xa.y * wq1.z + xa.z * wq2.z + xa.w * wq3.z;
            acc[i][3] += xa.x * wq0.w + xa.y * wq1.w + xa.z * wq2.w + xa.w * wq3.w;
        }
    }

    float4 cbv = *(const float4*)&cb[og];
    #pragma unroll
    for (int i = 0; i < 4; ++i) {
        acc[i][0] += cbv.x; acc[i][1] += cbv.y;
        acc[i][2] += cbv.z; acc[i][3] += cbv.w;
    }

    // LN over 256 channels: wave-local reduce (16 cg lanes) then cross-wave via LDS
    float s[4], ss[4];
    #pragma unroll
    for (int i = 0; i < 4; ++i) {
        s[i]  = acc[i][0] + acc[i][1] + acc[i][2] + acc[i][3];
        ss[i] = acc[i][0]*acc[i][0] + acc[i][1]*acc[i][1]
              + acc[i][2]*acc[i][2] + acc[i][3]*acc[i][3];
        #pragma unroll
        for (int d = 1; d < 16; d <<= 1) {
            s[i]  += __shfl_xor(s[i], d, 64);
            ss[i] += __shfl_xor(ss[i], d, 64);
        }
    }
    __syncthreads();   // done reading xin as image; reuse as scratch
    if ((lane & 15) == 0) {
        #pragma unroll
        for (int i = 0; i < 4; ++i) {
            int px = pxb + i;
            xin[(px * 4 + wave) * 2]     = s[i];
            xin[(px * 4 + wave) * 2 + 1] = ss[i];
        }
    }
    __syncthreads();

    float4 gv = *(const float4*)&g[og];
    float4 bv = *(const float4*)&bb[og];
    #pragma unroll
    for (int i = 0; i < 4; ++i) {
        int px = pxb + i;
        float S = 0.f, SS = 0.f;
        #pragma unroll
        for (int w = 0; w < 4; ++w) {
            S  += xin[(px * 4 + w) * 2];
            SS += xin[(px * 4 + w) * 2 + 1];
        }
        float m = S * (1.f / 256.f);
        float var = SS * (1.f / 256.f) - m * m;
        float rs = rsqrtf(var + 1e-5f);
        float4 y;
        y.x = gelu_exact((acc[i][0] - m) * rs * gv.x + bv.x);
        y.y = gelu_exact((acc[i][1] - m) * rs * gv.y + bv.y);
        y.z = gelu_exact((acc[i][2] - m) * rs * gv.z + bv.z);
        y.w = gelu_exact((acc[i][3] - m) * rs * gv.w + bv.w);
        *(float4*)&out[(size_t)bt * 4096 + px * 256 + og] = y;
    }
}

// ---------------------------------------------------------------------------
// K3: fc (1024,4096)@(4096,512)+b. grid 256 = 128 row-groups(8) x 2 col-halves.
// ---------------------------------------------------------------------------
__global__ __launch_bounds__(256) void k_fc(
        const float* __restrict__ a, const float* __restrict__ w,
        const float* __restrict__ bias, float* __restrict__ emb) {
    __shared__ __align__(16) float al[8 * 512];   // 16KB A-chunk

    int blk = blockIdx.x;
    int grp = blk >> 1, half = blk & 1;
    int tid = threadIdx.x;
    int o = half * 256 + tid;
    int row0 = grp * 8;

    float acc[8];
    #pragma unroll
    for (int r = 0; r < 8; ++r) acc[r] = 0.f;

    for (int kc = 0; kc < 8; ++kc) {
        __syncthreads();
        for (int i = tid; i < 4096; i += 256) {
            int r = i >> 9, kk = i & 511;
            al[i] = a[(size_t)(row0 + r) * 4096 + kc * 512 + kk];
        }
        __syncthreads();
        #pragma unroll 2
        for (int kk = 0; kk < 512; kk += 4) {
            size_t kg = (size_t)(kc * 512 + kk);
            float w0 = w[kg * 512 + o];
            float w1_ = w[(kg + 1) * 512 + o];
            float w2_ = w[(kg + 2) * 512 + o];
            float w3_ = w[(kg + 3) * 512 + o];
            #pragma unroll
            for (int r = 0; r < 8; ++r) {
                float4 a4 = *(const float4*)&al[r * 512 + kk];
                acc[r] += a4.x * w0 + a4.y * w1_ + a4.z * w2_ + a4.w * w3_;
            }
        }
    }
    float bv = bias[o];
    #pragma unroll
    for (int r = 0; r < 8; ++r)
        emb[(size_t)(row0 + r) * 512 + o] = acc[r] + bv;
}

// ---------------------------------------------------------------------------
// K4: Fourier gating. grid = B(64). DFT over T=16, freqs 1..8, ortho (x0.25).
// weights[b,e] = (mean_d amp) @ w_gate ; top-2 + softmax -> topi/topw.
// ---------------------------------------------------------------------------
__global__ __launch_bounds__(256) void k_gate(
        const float* __restrict__ emb, const float* __restrict__ wg,
        float* __restrict__ topw, int* __restrict__ topi) {
    __shared__ float ct[128], st[128];
    __shared__ float red[32];

    int b = blockIdx.x, tid = threadIdx.x;
    if (tid < 128) {
        int f = tid >> 4, t = tid & 15;
        int m16 = ((f + 1) * t) & 15;       // exact mod-16 angle reduction
        float ang = 3.14159265358979323846f * (float)m16 * 0.125f;
        ct[tid] = cosf(ang);
        st[tid] = sinf(ang);
    }
    __syncthreads();

    float ampsum[8] = {0,0,0,0,0,0,0,0};
    #pragma unroll
    for (int dd = 0; dd < 2; ++dd) {
        int d = tid + dd * 256;
        float v[16];
        #pragma unroll
        for (int t = 0; t < 16; ++t)
            v[t] = emb[((size_t)b * 16 + t) * 512 + d];
        #pragma unroll
        for (int f = 0; f < 8; ++f) {
            float re = v[0];   // t=0: cos=1, sin=0
            float im = 0.f;
            #pragma unroll
            for (int t = 1; t < 16; ++t) {
                re += v[t] * ct[f * 16 + t];
                im += v[t] * st[f * 16 + t];
            }
            ampsum[f] += sqrtf(re * re + im * im);
        }
    }
    int lane = tid & 63, wave = tid >> 6;
    #pragma unroll
    for (int f = 0; f < 8; ++f) {
        float sv = ampsum[f];
        #pragma unroll
        for (int d = 1; d < 64; d <<= 1) sv += __shfl_xor(sv, d, 64);
        if (lane == 0) red[wave * 8 + f] = sv;
    }
    __syncthreads();
    if (tid == 0) {
        float wts[6];
        #pragma unroll
        for (int e = 0; e < 6; ++e) wts[e] = 0.f;
        #pragma unroll
        for (int f = 0; f < 8; ++f) {
            float S = (red[f] + red[8 + f] + red[16 + f] + red[24 + f])
                      * (0.25f / 512.0f);   // ortho norm * mean over D
            #pragma unroll
            for (int e = 0; e < 6; ++e) wts[e] += S * wg[f * 6 + e];
        }
        int i1 = 0;
        for (int e = 1; e < 6; ++e) if (wts[e] > wts[i1]) i1 = e;
        int i2 = -1;
        for (int e = 0; e < 6; ++e)
            if (e != i1 && (i2 < 0 || wts[e] > wts[i2])) i2 = e;
        float ex = expf(wts[i2] - wts[i1]);
        float den = 1.0f + ex;
        topw[b * 2] = 1.0f / den;
        topw[b * 2 + 1] = ex / den;
        topi[b * 2] = i1;
        topi[b * 2 + 1] = i2;
    }
}

// ---------------------------------------------------------------------------
// K5: routed experts + exp/sum/log combine.
// grid 256 = b(64) x rowgroup(2, 8 rows) x fhalf(2). block 256 (one f each).
// ---------------------------------------------------------------------------
__global__ __launch_bounds__(256) void k_expert(
        const float* __restrict__ emb, const float* __restrict__ ew,
        const float* __restrict__ eb, const float* __restrict__ topw,
        const int* __restrict__ topi, float* __restrict__ out) {
    __shared__ __align__(16) float el[8 * 512];

    int blk = blockIdx.x;
    int b = blk >> 2, rg = (blk >> 1) & 1, fh = blk & 1;
    int tid = threadIdx.x;
    int f = fh * 256 + tid;
    int row0 = b * 16 + rg * 8;

    for (int i = tid; i < 4096; i += 256) {
        int r = i >> 9, k = i & 511;
        el[i] = emb[(size_t)(row0 + r) * 512 + k];
    }
    int e1 = topi[b * 2], e2 = topi[b * 2 + 1];
    float g1 = topw[b * 2], g2 = topw[b * 2 + 1];
    const float* w1p = ew + (size_t)e1 * 262144;
    const float* w2p = ew + (size_t)e2 * 262144;

    float acc1[8], acc2[8];
    #pragma unroll
    for (int r = 0; r < 8; ++r) { acc1[r] = 0.f; acc2[r] = 0.f; }
    __syncthreads();

    #pragma unroll 2
    for (int k = 0; k < 512; k += 4) {
        float w1a = w1p[(size_t)k * 512 + f];
        float w1b = w1p[(size_t)(k + 1) * 512 + f];
        float w1c = w1p[(size_t)(k + 2) * 512 + f];
        float w1d = w1p[(size_t)(k + 3) * 512 + f];
        float w2a = w2p[(size_t)k * 512 + f];
        float w2b = w2p[(size_t)(k + 1) * 512 + f];
        float w2c = w2p[(size_t)(k + 2) * 512 + f];
        float w2d = w2p[(size_t)(k + 3) * 512 + f];
        #pragma unroll
        for (int r = 0; r < 8; ++r) {
            float4 a4 = *(const float4*)&el[r * 512 + k];
            acc1[r] += a4.x * w1a + a4.y * w1b + a4.z * w1c + a4.w * w1d;
            acc2[r] += a4.x * w2a + a4.y * w2b + a4.z * w2c + a4.w * w2d;
        }
    }
    float b1 = eb[e1 * 512 + f], b2 = eb[e2 * 512 + f];
    #pragma unroll
    for (int r = 0; r < 8; ++r) {
        float c = g1 * expf(acc1[r] + b1) + g2 * expf(acc2[r] + b2);
        if (c == 0.f) c = EPS_;
        out[(size_t)(row0 + r) * 512 + f] = logf(c);
    }
}

// ---------------------------------------------------------------------------
extern "C" void kernel_launch(void* const* d_in, const int* in_sizes, int n_in,
                              void* d_out, int out_size, void* d_ws, size_t ws_size,
                              hipStream_t stream) {
    (void)in_sizes; (void)n_in; (void)out_size; (void)ws_size;
    const float* x   = (const float*)d_in[0];
    const float* c1w = (const float*)d_in[1];
    const float* c1b = (const float*)d_in[2];
    const float* l1g = (const float*)d_in[3];
    const float* l1b = (const float*)d_in[4];
    const float* c2w = (const float*)d_in[5];
    const float* c2b = (const float*)d_in[6];
    const float* l2g = (const float*)d_in[7];
    const float* l2b = (const float*)d_in[8];
    const float* fcw = (const float*)d_in[9];
    const float* fcb = (const float*)d_in[10];
    const float* wg  = (const float*)d_in[11];
    const float* ew  = (const float*)d_in[12];
    const float* eb  = (const float*)d_in[13];
    float* out = (float*)d_out;

    float* ws   = (float*)d_ws;
    float* w1r  = ws;                       // 16384
    float* w2r  = w1r + 16384;              // 262144
    float* s1   = w2r + 262144;             // 16777216 (BT,16,16,64)
    float* s2   = s1 + 16777216;            // 4194304  (BT,4096)
    float* emb  = s2 + 4194304;             // 524288   (BT,512)
    float* topw = emb + 524288;             // 128
    int*   topi = (int*)(topw + 128);       // 128

    hipLaunchKernelGGL(k_reorder, dim3(1024), dim3(256), 0, stream, c1w, c2w, w1r, w2r);
    hipLaunchKernelGGL(k_conv1, dim3(16384), dim3(256), 0, stream, x, w1r, c1b, l1g, l1b, s1);
    hipLaunchKernelGGL(k_conv2, dim3(1024), dim3(256), 0, stream, s1, w2r, c2b, l2g, l2b, s2);
    hipLaunchKernelGGL(k_fc, dim3(256), dim3(256), 0, stream, s2, fcw, fcb, emb);
    hipLaunchKernelGGL(k_gate, dim3(64), dim3(256), 0, stream, emb, wg, topw, topi);
    hipLaunchKernelGGL(k_expert, dim3(256), dim3(256), 0, stream, emb, ew, eb, topw, topi, out);
}

// Round 2
// 1031.467 us; speedup vs baseline: 1.2132x; 1.2132x over previous
//
#include <hip/hip_runtime.h>
#include <math.h>

#define EPS_  2.220446049250313e-16f

__device__ __forceinline__ float gelu_exact(float x) {
    return 0.5f * x * (1.0f + erff(x * 0.70710678118654752f));
}

// ---------------------------------------------------------------------------
// K0: reorder conv weights OIHW -> [k = kh*kW*C + kw*C + c][o]
// ---------------------------------------------------------------------------
__global__ __launch_bounds__(256) void k_reorder(
        const float* __restrict__ w1, const float* __restrict__ w2,
        float* __restrict__ w1r, float* __restrict__ w2r) {
    int i = blockIdx.x * 256 + threadIdx.x;
    if (i < 16384) {                 // conv1: (64,16,4,4) -> (256,64)
        int o = i & 63, r = i >> 6;
        int c = r & 15; r >>= 4;
        int kw = r & 3, kh = r >> 2;
        w1r[i] = w1[((o * 16 + c) * 4 + kh) * 4 + kw];
    }
    if (i < 262144) {                // conv2: (256,64,4,4) -> (1024,256)
        int o = i & 255, r = i >> 8;
        int c = r & 63; r >>= 6;
        int kw = r & 3, kh = r >> 2;
        w2r[i] = w2[((o * 64 + c) * 4 + kh) * 4 + kw];
    }
}

// ---------------------------------------------------------------------------
// K1: conv1 (patch-GEMM 256->64) + LN(64) + gelu
// grid = BT*4 (bt, ohg).  lanes <-> 64 pixels (oh=lane>>4, ow=lane&15),
// waves <-> 16-cout groups.  Weights: wave-uniform scalar loads.
// x in LDS with XOR bank swizzle: col^=(oh&1), c4^=(ow&3)  -> structural-min
// banking for the scattered b128 reads, in exactly 64 KB.
// ---------------------------------------------------------------------------
__global__ __launch_bounds__(256) void k_conv1(
        const float* __restrict__ x, const float* __restrict__ w1r,
        const float* __restrict__ cb, const float* __restrict__ g,
        const float* __restrict__ bb, float* __restrict__ out) {
    __shared__ __align__(16) float xin[16384];   // 64 KB

    int blk = blockIdx.x;
    int bt = blk >> 2, ohg = blk & 3;
    int tid = threadIdx.x;
    int lane = tid & 63;
    int wave = __builtin_amdgcn_readfirstlane(tid >> 6);
    int oh = lane >> 4, ow = lane & 15;

    // stage 16 input rows (contiguous 64 KB) with swizzle
    const float* xsrc = x + (size_t)bt * 65536 + (size_t)ohg * 16384;
    #pragma unroll
    for (int it = 0; it < 16; ++it) {
        int i = it * 256 + tid;              // quad index 0..4095
        int row = i >> 8, col = (i >> 2) & 63, c4 = i & 3;
        float4 v = *(const float4*)(xsrc + (size_t)i * 4);
        int colp = col ^ ((row >> 2) & 1);
        int c4p  = c4 ^ ((col >> 2) & 3);
        *(float4*)&xin[row * 1024 + colp * 16 + c4p * 4] = v;
    }
    __syncthreads();

    const float* wbase = w1r + wave * 16;    // uniform -> s_load path
    float acc[16];
    #pragma unroll
    for (int j = 0; j < 16; ++j) acc[j] = 0.f;

    int swc = ow & 3;    // c4 xor key
    int swl = oh & 1;    // col xor key
    #pragma unroll
    for (int kh = 0; kh < 4; ++kh) {
        int rowb = (oh * 4 + kh) * 1024;
        #pragma unroll
        for (int kw = 0; kw < 4; ++kw) {
            int colp = (ow * 4 + kw) ^ swl;
            int xb = rowb + colp * 16;
            #pragma unroll
            for (int c4 = 0; c4 < 4; ++c4) {
                float4 x4 = *(const float4*)&xin[xb + ((c4 ^ swc) << 2)];
                int k = kh * 64 + kw * 16 + c4 * 4;
                const float* wr = wbase + (size_t)k * 64;
                #pragma unroll
                for (int t = 0; t < 4; ++t) {
                    float xv = (t == 0) ? x4.x : (t == 1) ? x4.y :
                               (t == 2) ? x4.z : x4.w;
                    const float* wt = wr + t * 64;
                    #pragma unroll
                    for (int j4 = 0; j4 < 4; ++j4) {
                        float4 wv = *(const float4*)(wt + j4 * 4);
                        acc[j4 * 4 + 0] += xv * wv.x;
                        acc[j4 * 4 + 1] += xv * wv.y;
                        acc[j4 * 4 + 2] += xv * wv.z;
                        acc[j4 * 4 + 3] += xv * wv.w;
                    }
                }
            }
        }
    }

    // conv bias (uniform loads), then LN stats
    #pragma unroll
    for (int j4 = 0; j4 < 4; ++j4) {
        float4 cv = *(const float4*)(cb + wave * 16 + j4 * 4);
        acc[j4 * 4 + 0] += cv.x; acc[j4 * 4 + 1] += cv.y;
        acc[j4 * 4 + 2] += cv.z; acc[j4 * 4 + 3] += cv.w;
    }
    float s = 0.f, ss = 0.f;
    #pragma unroll
    for (int j = 0; j < 16; ++j) { s += acc[j]; ss += acc[j] * acc[j]; }

    __syncthreads();                 // xin no longer needed as image
    xin[lane * 4 + wave] = s;
    xin[256 + lane * 4 + wave] = ss;
    __syncthreads();
    float S  = xin[lane*4+0] + xin[lane*4+1] + xin[lane*4+2] + xin[lane*4+3];
    float SS = xin[256+lane*4+0] + xin[256+lane*4+1]
             + xin[256+lane*4+2] + xin[256+lane*4+3];
    float m = S * (1.f / 64.f);
    float var = SS * (1.f / 64.f) - m * m;
    float rs = rsqrtf(var + 1e-5f);

    // gelu + store: s1[bt][row=ohg*4+oh][col=ow][c=wave*16+j]
    size_t obase = (size_t)bt * 16384 + (size_t)((ohg * 4 + oh) * 16 + ow) * 64
                 + wave * 16;
    #pragma unroll
    for (int j4 = 0; j4 < 4; ++j4) {
        float4 gv = *(const float4*)(g + wave * 16 + j4 * 4);
        float4 bv = *(const float4*)(bb + wave * 16 + j4 * 4);
        float4 y;
        y.x = gelu_exact((acc[j4*4+0] - m) * rs * gv.x + bv.x);
        y.y = gelu_exact((acc[j4*4+1] - m) * rs * gv.y + bv.y);
        y.z = gelu_exact((acc[j4*4+2] - m) * rs * gv.z + bv.z);
        y.w = gelu_exact((acc[j4*4+3] - m) * rs * gv.w + bv.w);
        *(float4*)&out[obase + j4 * 4] = y;
    }
}

// ---------------------------------------------------------------------------
// K2: conv2 (patch-GEMM 1024->256) + LN(256) + gelu
// grid = BT.  Image in LDS as [px][k] (so x-reads are wave-uniform
// broadcasts -> no bank conflicts).  waves <-> K-quarters (256 each),
// lanes <-> 4-cout groups (og = lane*4).  Weights streamed coalesced from
// global (L2-resident).  Cross-wave K reduction via swizzled LDS scratch.
// ---------------------------------------------------------------------------
__global__ __launch_bounds__(256) void k_conv2(
        const float* __restrict__ s1, const float* __restrict__ w2r,
        const float* __restrict__ cb, const float* __restrict__ g,
        const float* __restrict__ bb, float* __restrict__ out) {
    __shared__ __align__(16) float xin[16384];   // 64 KB

    int bt = blockIdx.x;
    int tid = threadIdx.x, lane = tid & 63;
    int wave = __builtin_amdgcn_readfirstlane(tid >> 6);

    // stage image rearranged (row,col,c) -> [px][k]
    const float* src = s1 + (size_t)bt * 16384;
    #pragma unroll
    for (int it = 0; it < 16; ++it) {
        int i = it * 256 + tid;              // quad 0..4095
        int row = i >> 8, col = (i >> 4) & 15, cq = i & 15;
        int px = (row >> 2) * 4 + (col >> 2);
        int dq = px * 256 + (row & 3) * 64 + (col & 3) * 16 + cq;
        *(float4*)&xin[dq * 4] = *(const float4*)(src + (size_t)i * 4);
    }
    __syncthreads();

    int og = lane * 4;
    float acc[16][4];
    #pragma unroll
    for (int p = 0; p < 16; ++p)
        #pragma unroll
        for (int j = 0; j < 4; ++j) acc[p][j] = 0.f;

    int kbase = wave * 256;
    for (int it = 0; it < 64; ++it) {
        int k = kbase + it * 4;
        float4 w0 = *(const float4*)&w2r[(size_t)(k + 0) * 256 + og];
        float4 w1v = *(const float4*)&w2r[(size_t)(k + 1) * 256 + og];
        float4 w2v = *(const float4*)&w2r[(size_t)(k + 2) * 256 + og];
        float4 w3v = *(const float4*)&w2r[(size_t)(k + 3) * 256 + og];
        #pragma unroll
        for (int px = 0; px < 16; ++px) {
            float4 x4 = *(const float4*)&xin[px * 1024 + k];  // broadcast
            acc[px][0] += x4.x*w0.x + x4.y*w1v.x + x4.z*w2v.x + x4.w*w3v.x;
            acc[px][1] += x4.x*w0.y + x4.y*w1v.y + x4.z*w2v.y + x4.w*w3v.y;
            acc[px][2] += x4.x*w0.z + x4.y*w1v.z + x4.z*w2v.z + x4.w*w3v.z;
            acc[px][3] += x4.x*w0.w + x4.y*w1v.w + x4.z*w2v.w + x4.w*w3v.w;
        }
    }

    // cross-wave K reduction: scratch[px][r][cq'] with cq' = cq ^ (px&7)
    __syncthreads();
    #pragma unroll
    for (int px = 0; px < 16; ++px) {
        int cqp = lane ^ (px & 7);
        float4 v; v.x = acc[px][0]; v.y = acc[px][1];
                  v.z = acc[px][2]; v.w = acc[px][3];
        *(float4*)&xin[px * 1024 + wave * 256 + cqp * 4] = v;
    }
    __syncthreads();

    int px = tid >> 4, cg = tid & 15;        // 16 threads per px (contig lanes)
    float vals[16];
    #pragma unroll
    for (int u = 0; u < 4; ++u) {
        int cqp = (cg * 4 + u) ^ (px & 7);
        float sx = 0.f, sy = 0.f, sz = 0.f, sw = 0.f;
        #pragma unroll
        for (int r = 0; r < 4; ++r) {
            float4 p = *(const float4*)&xin[px * 1024 + r * 256 + cqp * 4];
            sx += p.x; sy += p.y; sz += p.z; sw += p.w;
        }
        vals[u*4+0] = sx; vals[u*4+1] = sy; vals[u*4+2] = sz; vals[u*4+3] = sw;
    }
    // bias
    #pragma unroll
    for (int u = 0; u < 4; ++u) {
        float4 cv = *(const float4*)(cb + cg * 16 + u * 4);
        vals[u*4+0] += cv.x; vals[u*4+1] += cv.y;
        vals[u*4+2] += cv.z; vals[u*4+3] += cv.w;
    }
    // LN over 256 channels: shfl across the 16 lanes sharing px
    float s = 0.f, ss = 0.f;
    #pragma unroll
    for (int j = 0; j < 16; ++j) { s += vals[j]; ss += vals[j] * vals[j]; }
    #pragma unroll
    for (int d = 1; d < 16; d <<= 1) {
        s  += __shfl_xor(s, d, 64);
        ss += __shfl_xor(ss, d, 64);
    }
    float m = s * (1.f / 256.f);
    float var = ss * (1.f / 256.f) - m * m;
    float rs = rsqrtf(var + 1e-5f);

    size_t obase = (size_t)bt * 4096 + (size_t)px * 256 + cg * 16;
    #pragma unroll
    for (int u = 0; u < 4; ++u) {
        float4 gv = *(const float4*)(g + cg * 16 + u * 4);
        float4 bv = *(const float4*)(bb + cg * 16 + u * 4);
        float4 y;
        y.x = gelu_exact((vals[u*4+0] - m) * rs * gv.x + bv.x);
        y.y = gelu_exact((vals[u*4+1] - m) * rs * gv.y + bv.y);
        y.z = gelu_exact((vals[u*4+2] - m) * rs * gv.z + bv.z);
        y.w = gelu_exact((vals[u*4+3] - m) * rs * gv.w + bv.w);
        *(float4*)&out[obase + u * 4] = y;
    }
}

// ---------------------------------------------------------------------------
// K3: fc partials. grid = 64 rowg(16 rows) x 4 kchunk(1024).
// A-chunk (16x1024 = 64KB) in LDS, broadcast reads; waves <-> 128-col
// quarters, lanes carry 2 cols; coalesced float2 weight streams.
// ---------------------------------------------------------------------------
__global__ __launch_bounds__(256) void k_fc(
        const float* __restrict__ a, const float* __restrict__ w,
        float* __restrict__ part) {
    __shared__ __align__(16) float al[16384];

    int blk = blockIdx.x;
    int rowg = blk >> 2, kc = blk & 3;
    int row0 = rowg * 16;
    int tid = threadIdx.x, lane = tid & 63;
    int wave = __builtin_amdgcn_readfirstlane(tid >> 6);

    #pragma unroll
    for (int it = 0; it < 16; ++it) {
        int i = it * 256 + tid;              // quad 0..4095
        int r = i >> 8, q = i & 255;
        *(float4*)&al[r * 1024 + q * 4] =
            *(const float4*)(a + (size_t)(row0 + r) * 4096 + kc * 1024 + q * 4);
    }
    __syncthreads();

    int co = wave * 128 + lane * 2;
    float acc[16][2];
    #pragma unroll
    for (int r = 0; r < 16; ++r) { acc[r][0] = 0.f; acc[r][1] = 0.f; }

    const float* wp = w + (size_t)kc * 1024 * 512 + co;
    for (int it = 0; it < 256; ++it) {
        int kk = it * 4;
        float2 w0 = *(const float2*)(wp + (size_t)(kk + 0) * 512);
        float2 w1v = *(const float2*)(wp + (size_t)(kk + 1) * 512);
        float2 w2v = *(const float2*)(wp + (size_t)(kk + 2) * 512);
        float2 w3v = *(const float2*)(wp + (size_t)(kk + 3) * 512);
        #pragma unroll
        for (int r = 0; r < 16; ++r) {
            float4 a4 = *(const float4*)&al[r * 1024 + kk];   // broadcast
            acc[r][0] += a4.x*w0.x + a4.y*w1v.x + a4.z*w2v.x + a4.w*w3v.x;
            acc[r][1] += a4.x*w0.y + a4.y*w1v.y + a4.z*w2v.y + a4.w*w3v.y;
        }
    }
    #pragma unroll
    for (int r = 0; r < 16; ++r) {
        float2 v; v.x = acc[r][0]; v.y = acc[r][1];
        *(float2*)&part[(size_t)kc * 524288 + (size_t)(row0 + r) * 512 + co] = v;
    }
}

// K3b: sum 4 K-partials + bias -> emb
__global__ __launch_bounds__(256) void k_fc_sum(
        const float* __restrict__ part, const float* __restrict__ bias,
        float* __restrict__ emb) {
    int i = blockIdx.x * 256 + threadIdx.x;   // float4 index, 131072 total
    size_t q = (size_t)i * 4;
    float4 s0 = *(const float4*)(part + q);
    float4 s1 = *(const float4*)(part + 524288 + q);
    float4 s2 = *(const float4*)(part + 1048576 + q);
    float4 s3 = *(const float4*)(part + 1572864 + q);
    float4 bv = *(const float4*)(bias + (q & 511));
    float4 r;
    r.x = s0.x + s1.x + s2.x + s3.x + bv.x;
    r.y = s0.y + s1.y + s2.y + s3.y + bv.y;
    r.z = s0.z + s1.z + s2.z + s3.z + bv.z;
    r.w = s0.w + s1.w + s2.w + s3.w + bv.w;
    *(float4*)(emb + q) = r;
}

// ---------------------------------------------------------------------------
// K4: Fourier gating (unchanged from passing round-1 version).
// ---------------------------------------------------------------------------
__global__ __launch_bounds__(256) void k_gate(
        const float* __restrict__ emb, const float* __restrict__ wg,
        float* __restrict__ topw, int* __restrict__ topi) {
    __shared__ float ct[128], st[128];
    __shared__ float red[32];

    int b = blockIdx.x, tid = threadIdx.x;
    if (tid < 128) {
        int f = tid >> 4, t = tid & 15;
        int m16 = ((f + 1) * t) & 15;
        float ang = 3.14159265358979323846f * (float)m16 * 0.125f;
        ct[tid] = cosf(ang);
        st[tid] = sinf(ang);
    }
    __syncthreads();

    float ampsum[8] = {0,0,0,0,0,0,0,0};
    #pragma unroll
    for (int dd = 0; dd < 2; ++dd) {
        int d = tid + dd * 256;
        float v[16];
        #pragma unroll
        for (int t = 0; t < 16; ++t)
            v[t] = emb[((size_t)b * 16 + t) * 512 + d];
        #pragma unroll
        for (int f = 0; f < 8; ++f) {
            float re = v[0];
            float im = 0.f;
            #pragma unroll
            for (int t = 1; t < 16; ++t) {
                re += v[t] * ct[f * 16 + t];
                im += v[t] * st[f * 16 + t];
            }
            ampsum[f] += sqrtf(re * re + im * im);
        }
    }
    int lane = tid & 63, wave = tid >> 6;
    #pragma unroll
    for (int f = 0; f < 8; ++f) {
        float sv = ampsum[f];
        #pragma unroll
        for (int d = 1; d < 64; d <<= 1) sv += __shfl_xor(sv, d, 64);
        if (lane == 0) red[wave * 8 + f] = sv;
    }
    __syncthreads();
    if (tid == 0) {
        float wts[6];
        #pragma unroll
        for (int e = 0; e < 6; ++e) wts[e] = 0.f;
        #pragma unroll
        for (int f = 0; f < 8; ++f) {
            float S = (red[f] + red[8 + f] + red[16 + f] + red[24 + f])
                      * (0.25f / 512.0f);
            #pragma unroll
            for (int e = 0; e < 6; ++e) wts[e] += S * wg[f * 6 + e];
        }
        int i1 = 0;
        for (int e = 1; e < 6; ++e) if (wts[e] > wts[i1]) i1 = e;
        int i2 = -1;
        for (int e = 0; e < 6; ++e)
            if (e != i1 && (i2 < 0 || wts[e] > wts[i2])) i2 = e;
        float ex = expf(wts[i2] - wts[i1]);
        float den = 1.0f + ex;
        topw[b * 2] = 1.0f / den;
        topw[b * 2 + 1] = ex / den;
        topi[b * 2] = i1;
        topi[b * 2 + 1] = i2;
    }
}

// ---------------------------------------------------------------------------
// K5: routed experts + exp/sum/log. grid = 64 b x 2 rowg(8 rows).
// emb rows in LDS (broadcast), waves <-> 128-f quarters, lanes carry 2 f.
// ---------------------------------------------------------------------------
__global__ __launch_bounds__(256) void k_expert(
        const float* __restrict__ emb, const float* __restrict__ ew,
        const float* __restrict__ eb, const float* __restrict__ topw,
        const int* __restrict__ topi, float* __restrict__ out) {
    __shared__ __align__(16) float el[4096];

    int blk = blockIdx.x;
    int b = blk >> 1, rg = blk & 1;
    int row0 = b * 16 + rg * 8;
    int tid = threadIdx.x, lane = tid & 63;
    int wave = __builtin_amdgcn_readfirstlane(tid >> 6);

    #pragma unroll
    for (int it = 0; it < 4; ++it) {
        int i = it * 256 + tid;              // quad 0..1023
        int r = i >> 7, q = i & 127;
        *(float4*)&el[r * 512 + q * 4] =
            *(const float4*)(emb + (size_t)(row0 + r) * 512 + q * 4);
    }
    int e1 = topi[b * 2], e2 = topi[b * 2 + 1];
    float g1 = topw[b * 2], g2 = topw[b * 2 + 1];
    int f = wave * 128 + lane * 2;
    const float* w1p = ew + (size_t)e1 * 262144 + f;
    const float* w2p = ew + (size_t)e2 * 262144 + f;

    float acc1[8][2], acc2[8][2];
    #pragma unroll
    for (int r = 0; r < 8; ++r) {
        acc1[r][0] = 0.f; acc1[r][1] = 0.f;
        acc2[r][0] = 0.f; acc2[r][1] = 0.f;
    }
    __syncthreads();

    for (int it = 0; it < 128; ++it) {
        int k = it * 4;
        float2 wa0 = *(const float2*)(w1p + (size_t)(k + 0) * 512);
        float2 wa1 = *(const float2*)(w1p + (size_t)(k + 1) * 512);
        float2 wa2 = *(const float2*)(w1p + (size_t)(k + 2) * 512);
        float2 wa3 = *(const float2*)(w1p + (size_t)(k + 3) * 512);
        float2 wb0 = *(const float2*)(w2p + (size_t)(k + 0) * 512);
        float2 wb1 = *(const float2*)(w2p + (size_t)(k + 1) * 512);
        float2 wb2 = *(const float2*)(w2p + (size_t)(k + 2) * 512);
        float2 wb3 = *(const float2*)(w2p + (size_t)(k + 3) * 512);
        #pragma unroll
        for (int r = 0; r < 8; ++r) {
            float4 a4 = *(const float4*)&el[r * 512 + k];     // broadcast
            acc1[r][0] += a4.x*wa0.x + a4.y*wa1.x + a4.z*wa2.x + a4.w*wa3.x;
            acc1[r][1] += a4.x*wa0.y + a4.y*wa1.y + a4.z*wa2.y + a4.w*wa3.y;
            acc2[r][0] += a4.x*wb0.x + a4.y*wb1.x + a4.z*wb2.x + a4.w*wb3.x;
            acc2[r][1] += a4.x*wb0.y + a4.y*wb1.y + a4.z*wb2.y + a4.w*wb3.y;
        }
    }
    float2 b1 = *(const float2*)(eb + e1 * 512 + f);
    float2 b2 = *(const float2*)(eb + e2 * 512 + f);
    #pragma unroll
    for (int r = 0; r < 8; ++r) {
        float c0 = g1 * expf(acc1[r][0] + b1.x) + g2 * expf(acc2[r][0] + b2.x);
        float c1 = g1 * expf(acc1[r][1] + b1.y) + g2 * expf(acc2[r][1] + b2.y);
        if (c0 == 0.f) c0 = EPS_;
        if (c1 == 0.f) c1 = EPS_;
        float2 v; v.x = logf(c0); v.y = logf(c1);
        *(float2*)&out[(size_t)(row0 + r) * 512 + f] = v;
    }
}

// ---------------------------------------------------------------------------
extern "C" void kernel_launch(void* const* d_in, const int* in_sizes, int n_in,
                              void* d_out, int out_size, void* d_ws, size_t ws_size,
                              hipStream_t stream) {
    (void)in_sizes; (void)n_in; (void)out_size; (void)ws_size;
    const float* x   = (const float*)d_in[0];
    const float* c1w = (const float*)d_in[1];
    const float* c1b = (const float*)d_in[2];
    const float* l1g = (const float*)d_in[3];
    const float* l1b = (const float*)d_in[4];
    const float* c2w = (const float*)d_in[5];
    const float* c2b = (const float*)d_in[6];
    const float* l2g = (const float*)d_in[7];
    const float* l2b = (const float*)d_in[8];
    const float* fcw = (const float*)d_in[9];
    const float* fcb = (const float*)d_in[10];
    const float* wg  = (const float*)d_in[11];
    const float* ew  = (const float*)d_in[12];
    const float* eb  = (const float*)d_in[13];
    float* out = (float*)d_out;

    float* ws   = (float*)d_ws;
    float* w1r  = ws;                       // 16384
    float* w2r  = w1r + 16384;              // 262144
    float* s1   = w2r + 262144;             // 16777216 (BT,16,16,64)
    float* s2   = s1 + 16777216;            // 4194304  (BT,4096)
    float* emb  = s2 + 4194304;             // 524288   (BT,512)
    float* topw = emb + 524288;             // 128
    int*   topi = (int*)(topw + 128);       // 128
    float* part = s1;                       // alias: s1 dead after conv2

    hipLaunchKernelGGL(k_reorder, dim3(1024), dim3(256), 0, stream, c1w, c2w, w1r, w2r);
    hipLaunchKernelGGL(k_conv1, dim3(4096), dim3(256), 0, stream, x, w1r, c1b, l1g, l1b, s1);
    hipLaunchKernelGGL(k_conv2, dim3(1024), dim3(256), 0, stream, s1, w2r, c2b, l2g, l2b, s2);
    hipLaunchKernelGGL(k_fc, dim3(256), dim3(256), 0, stream, s2, fcw, part);
    hipLaunchKernelGGL(k_fc_sum, dim3(512), dim3(256), 0, stream, part, fcb, emb);
    hipLaunchKernelGGL(k_gate, dim3(64), dim3(256), 0, stream, emb, wg, topw, topi);
    hipLaunchKernelGGL(k_expert, dim3(128), dim3(256), 0, stream, emb, ew, eb, topw, topi, out);
}

// Round 4
// 566.475 us; speedup vs baseline: 2.2091x; 1.8209x over previous
//
#include <hip/hip_runtime.h>
#include <math.h>

#define EPS_  2.220446049250313e-16f

using bf16x8 = __attribute__((ext_vector_type(8))) short;
using f32x4  = __attribute__((ext_vector_type(4))) float;

__device__ __forceinline__ float gelu_exact(float x) {
    return 0.5f * x * (1.0f + erff(x * 0.70710678118654752f));
}

__device__ __forceinline__ unsigned short f2bf(float f) {
    unsigned u = __builtin_bit_cast(unsigned, f);
    u += 0x7FFF + ((u >> 16) & 1);              // RNE
    return (unsigned short)(u >> 16);
}

__device__ __forceinline__ bf16x8 pack8(float4 a, float4 b) {
    bf16x8 r;
    r[0] = (short)f2bf(a.x); r[1] = (short)f2bf(a.y);
    r[2] = (short)f2bf(a.z); r[3] = (short)f2bf(a.w);
    r[4] = (short)f2bf(b.x); r[5] = (short)f2bf(b.y);
    r[6] = (short)f2bf(b.z); r[7] = (short)f2bf(b.w);
    return r;
}

#define MFMA(a, b, c) __builtin_amdgcn_mfma_f32_16x16x32_bf16(a, b, c, 0, 0, 0)

// ---------------------------------------------------------------------------
// K0: convert all weights to bf16 MFMA B-fragment buffers.
// Fragment layout per 16x16x32 tile: lane l holds B[k0*32+(l>>4)*8+j][n0+(l&15)],
// j=0..7 contiguous -> one dwordx4 per lane at runtime.
// Ranges: conv1 32 tiles [0,2048); conv2 512 tiles [2048,34816);
//         fc 4096 tiles [34816,296960); experts 3072 tiles [296960,493568).
// ---------------------------------------------------------------------------
__global__ __launch_bounds__(256) void k_prep(
        const float* __restrict__ w1, const float* __restrict__ w2,
        const float* __restrict__ fcw, const float* __restrict__ ew,
        unsigned short* __restrict__ frag1, unsigned short* __restrict__ frag2,
        unsigned short* __restrict__ fragF, unsigned short* __restrict__ fragE) {
    int t = blockIdx.x * 256 + threadIdx.x;
    int lane = t & 63, col = lane & 15, grp = (lane >> 4) & 3;
    bf16x8 r;
    if (t < 2048) {                              // conv1: k=kh*64+kw*16+c, N=64
        int tile = t >> 6, nt = tile >> 3, ki = tile & 7;
        int n = nt * 16 + col;
        #pragma unroll
        for (int j = 0; j < 8; ++j) {
            int k = ki * 32 + grp * 8 + j;
            int kh = k >> 6, kw = (k >> 4) & 3, c = k & 15;
            r[j] = (short)f2bf(w1[((n * 16 + c) * 4 + kh) * 4 + kw]);
        }
        ((bf16x8*)frag1)[t] = r;
    } else if (t < 34816) {                      // conv2: k=kh*256+kw*64+c, N=256
        int u = t - 2048;                        // 32768 threads: 16 nt x 32 kk
        int tile = u >> 6, nt = tile >> 5, kk = tile & 31;
        int n = nt * 16 + col;
        #pragma unroll
        for (int j = 0; j < 8; ++j) {
            int k = kk * 32 + grp * 8 + j;
            int kh = k >> 8, kw = (k >> 6) & 3, c = k & 63;
            r[j] = (short)f2bf(w2[((n * 64 + c) * 4 + kh) * 4 + kw]);
        }
        ((bf16x8*)frag2)[u] = r;
    } else if (t < 296960) {                     // fc: row-major [k][n], 32 nt x 128 kk
        int u = t - 34816;
        int tile = u >> 6, nt = tile >> 7, kk = tile & 127;
        int n = nt * 16 + col;
        #pragma unroll
        for (int j = 0; j < 8; ++j) {
            int k = kk * 32 + grp * 8 + j;
            r[j] = (short)f2bf(fcw[(size_t)k * 512 + n]);
        }
        ((bf16x8*)fragF)[u] = r;
    } else if (t < 493568) {                     // experts: [e][k][n], 6 x 32 nt x 16 kk
        int u = t - 296960;
        int tile = u >> 6, e = tile >> 9, rem = tile & 511;
        int nt = rem >> 4, kk = rem & 15;
        int n = nt * 16 + col;
        #pragma unroll
        for (int j = 0; j < 8; ++j) {
            int k = kk * 32 + grp * 8 + j;
            r[j] = (short)f2bf(ew[((size_t)e * 512 + k) * 512 + n]);
        }
        ((bf16x8*)fragE)[u] = r;
    }
}

// ---------------------------------------------------------------------------
// K1: conv1 MFMA (M=128 px per block, N=64, K=256) + LN(64) + gelu -> s1 bf16
// grid 2048 = bt(1024) x half(2).  4 waves; wave owns M-tiles {2w,2w+1}.
// A in LDS bf16 [px][k], 16B-unit index kq swizzled kq^(px&7).
// ---------------------------------------------------------------------------
__global__ __launch_bounds__(256) void k_conv1(
        const float* __restrict__ x, const unsigned short* __restrict__ frag1,
        const float* __restrict__ cb, const float* __restrict__ g,
        const float* __restrict__ bb, unsigned short* __restrict__ s1b) {
    __shared__ unsigned short lds[32768];        // 64 KB

    int blk = blockIdx.x;
    int bt = blk >> 1, half = blk & 1;
    int tid = threadIdx.x, lane = tid & 63;
    int wave = __builtin_amdgcn_readfirstlane(tid >> 6);
    int col = lane & 15, grp = lane >> 4, sw = col & 7;

    // stage x (fp32) -> bf16 LDS
    const float* xb = x + (size_t)bt * 65536 + half * 32768;
    #pragma unroll
    for (int it = 0; it < 16; ++it) {
        int i = it * 256 + tid;                  // 0..4095 (16B units)
        int q8 = i & 7, ow = (i >> 3) & 15, kh = (i >> 7) & 3, ohl = (i >> 9) & 7;
        const float* p = xb + ((ohl * 4 + kh) * 1024 + ow * 64 + q8 * 8);
        float4 v0 = *(const float4*)p;
        float4 v1 = *(const float4*)(p + 4);
        int pxl = ohl * 16 + ow;
        int kq = (kh * 8 + q8) ^ (pxl & 7);
        ((bf16x8*)lds)[pxl * 32 + kq] = pack8(v0, v1);
    }
    __syncthreads();

    f32x4 acc[2][4];
    #pragma unroll
    for (int m = 0; m < 2; ++m)
        #pragma unroll
        for (int n = 0; n < 4; ++n) acc[m][n] = (f32x4)(0.f);

    const bf16x8* Af = (const bf16x8*)lds;
    const bf16x8* Bf = (const bf16x8*)frag1;
    int mt0 = wave * 2;
    #pragma unroll
    for (int ki = 0; ki < 8; ++ki) {
        bf16x8 a0 = Af[(mt0 * 16 + col) * 32 + ((ki * 4 + grp) ^ sw)];
        bf16x8 a1 = Af[((mt0 + 1) * 16 + col) * 32 + ((ki * 4 + grp) ^ sw)];
        #pragma unroll
        for (int nt = 0; nt < 4; ++nt) {
            bf16x8 b = Bf[(nt * 8 + ki) * 64 + lane];
            acc[0][nt] = MFMA(a0, b, acc[0][nt]);
            acc[1][nt] = MFMA(a1, b, acc[1][nt]);
        }
    }

    // conv bias, LN(64) stats via 16-lane shuffles (cols live in lane&15)
    float cbv[4], gv[4], bv[4];
    #pragma unroll
    for (int nt = 0; nt < 4; ++nt) {
        cbv[nt] = cb[nt * 16 + col];
        gv[nt]  = g[nt * 16 + col];
        bv[nt]  = bb[nt * 16 + col];
    }
    #pragma unroll
    for (int m = 0; m < 2; ++m) {
        float s[4], ss[4];
        #pragma unroll
        for (int j = 0; j < 4; ++j) { s[j] = 0.f; ss[j] = 0.f; }
        #pragma unroll
        for (int nt = 0; nt < 4; ++nt)
            #pragma unroll
            for (int j = 0; j < 4; ++j) {
                float v = acc[m][nt][j] + cbv[nt];
                acc[m][nt][j] = v;
                s[j] += v; ss[j] += v * v;
            }
        #pragma unroll
        for (int j = 0; j < 4; ++j) {
            #pragma unroll
            for (int d = 1; d < 16; d <<= 1) {
                s[j]  += __shfl_xor(s[j], d, 64);
                ss[j] += __shfl_xor(ss[j], d, 64);
            }
            float mm = s[j] * (1.f / 64.f);
            float var = ss[j] * (1.f / 64.f) - mm * mm;
            float rs = rsqrtf(var + 1e-5f);
            int pxl = (mt0 + m) * 16 + grp * 4 + j;
            #pragma unroll
            for (int nt = 0; nt < 4; ++nt) {
                float y = gelu_exact((acc[m][nt][j] - mm) * rs * gv[nt] + bv[nt]);
                // own-wave rows only -> no barrier needed (wave-ordered LDS)
                lds[pxl * 256 + nt * 16 + col] = f2bf(y);
            }
        }
    }

    // coalesced bf16 write-out of own rows
    size_t gb = ((size_t)bt * 256 + half * 128 + wave * 32) * 8;  // 16B units
    #pragma unroll
    for (int it = 0; it < 4; ++it) {
        int u = it * 64 + lane;                  // 0..255
        int pxl_loc = u >> 3, cq = u & 7;
        bf16x8 v = ((const bf16x8*)lds)[(wave * 32 + pxl_loc) * 32 + cq];
        ((bf16x8*)s1b)[gb + pxl_loc * 8 + cq] = v;
    }
}

// ---------------------------------------------------------------------------
// K2: conv2 MFMA (M=64 px, N=256, K=1024 in 4 chunks) + LN(256) + gelu -> s2 bf16
// grid 256.  4 waves; wave owns N-quarter (4 N-tiles), all 4 M-tiles shared.
// ---------------------------------------------------------------------------
__global__ __launch_bounds__(256) void k_conv2(
        const unsigned short* __restrict__ s1b, const unsigned short* __restrict__ frag2,
        const float* __restrict__ cb, const float* __restrict__ g,
        const float* __restrict__ bb, unsigned short* __restrict__ s2b) {
    __shared__ unsigned short lds[16384];        // 32 KB A / epilogue
    __shared__ float sc[512];                    // LN cross-wave scratch

    int blk = blockIdx.x;
    int pxg0 = blk * 64;
    int tid = threadIdx.x, lane = tid & 63;
    int wave = __builtin_amdgcn_readfirstlane(tid >> 6);
    int col = lane & 15, grp = lane >> 4, sw = col & 7;

    f32x4 acc[4][4];
    #pragma unroll
    for (int m = 0; m < 4; ++m)
        #pragma unroll
        for (int n = 0; n < 4; ++n) acc[m][n] = (f32x4)(0.f);

    const bf16x8* Af = (const bf16x8*)lds;
    const bf16x8* Bf = (const bf16x8*)frag2;
    int nt0 = wave * 4;

    for (int kc = 0; kc < 4; ++kc) {
        if (kc) __syncthreads();
        #pragma unroll
        for (int it = 0; it < 8; ++it) {
            int i = it * 256 + tid;              // 0..2047
            int pxl = i >> 5, kq = i & 31;
            int pxg = pxg0 + pxl, bt = pxg >> 4, pxi = pxg & 15;
            int row = (pxi >> 2) * 4 + kc, colb = (pxi & 3) * 4;
            bf16x8 v = ((const bf16x8*)s1b)[((size_t)bt * 256 + row * 16 + colb) * 8 + kq];
            ((bf16x8*)lds)[pxl * 32 + (kq ^ (pxl & 7))] = v;
        }
        __syncthreads();
        #pragma unroll
        for (int ki = 0; ki < 8; ++ki) {
            int kk = kc * 8 + ki;
            bf16x8 a[4];
            #pragma unroll
            for (int m = 0; m < 4; ++m)
                a[m] = Af[(m * 16 + col) * 32 + ((ki * 4 + grp) ^ sw)];
            #pragma unroll
            for (int n = 0; n < 4; ++n) {
                bf16x8 b = Bf[((nt0 + n) * 32 + kk) * 64 + lane];
                #pragma unroll
                for (int m = 0; m < 4; ++m)
                    acc[m][n] = MFMA(a[m], b, acc[m][n]);
            }
        }
    }

    // bias + wave-local stats
    float cbv[4], gv[4], bv[4];
    #pragma unroll
    for (int n = 0; n < 4; ++n) {
        cbv[n] = cb[(nt0 + n) * 16 + col];
        gv[n]  = g[(nt0 + n) * 16 + col];
        bv[n]  = bb[(nt0 + n) * 16 + col];
    }
    float s[4][4], ss[4][4];
    #pragma unroll
    for (int m = 0; m < 4; ++m)
        #pragma unroll
        for (int j = 0; j < 4; ++j) { s[m][j] = 0.f; ss[m][j] = 0.f; }
    #pragma unroll
    for (int m = 0; m < 4; ++m)
        #pragma unroll
        for (int n = 0; n < 4; ++n)
            #pragma unroll
            for (int j = 0; j < 4; ++j) {
                float v = acc[m][n][j] + cbv[n];
                acc[m][n][j] = v;
                s[m][j] += v; ss[m][j] += v * v;
            }
    #pragma unroll
    for (int m = 0; m < 4; ++m)
        #pragma unroll
        for (int j = 0; j < 4; ++j) {
            #pragma unroll
            for (int d = 1; d < 16; d <<= 1) {
                s[m][j]  += __shfl_xor(s[m][j], d, 64);
                ss[m][j] += __shfl_xor(ss[m][j], d, 64);
            }
        }
    if (col == 0) {
        #pragma unroll
        for (int m = 0; m < 4; ++m)
            #pragma unroll
            for (int j = 0; j < 4; ++j) {
                int px = m * 16 + grp * 4 + j;
                sc[px * 8 + wave] = s[m][j];
                sc[px * 8 + 4 + wave] = ss[m][j];
            }
    }
    __syncthreads();   // also guarantees all MFMA A-reads done -> lds reusable

    #pragma unroll
    for (int m = 0; m < 4; ++m)
        #pragma unroll
        for (int j = 0; j < 4; ++j) {
            int px = m * 16 + grp * 4 + j;
            float4 Sv  = *(const float4*)&sc[px * 8];
            float4 SSv = *(const float4*)&sc[px * 8 + 4];
            float S  = Sv.x + Sv.y + Sv.z + Sv.w;
            float SS = SSv.x + SSv.y + SSv.z + SSv.w;
            float mm = S * (1.f / 256.f);
            float var = SS * (1.f / 256.f) - mm * mm;
            float rs = rsqrtf(var + 1e-5f);
            #pragma unroll
            for (int n = 0; n < 4; ++n) {
                float y = gelu_exact((acc[m][n][j] - mm) * rs * gv[n] + bv[n]);
                lds[px * 256 + (nt0 + n) * 16 + col] = f2bf(y);
            }
        }
    __syncthreads();

    // coalesced bf16 out: s2b[pxg][256]
    #pragma unroll
    for (int it = 0; it < 8; ++it) {
        int u = it * 256 + tid;                  // 0..2047
        int pxl = u >> 5, cq = u & 31;
        bf16x8 v = ((const bf16x8*)lds)[pxl * 32 + cq];
        ((bf16x8*)s2b)[((size_t)(pxg0 + pxl)) * 32 + cq] = v;
    }
}

// ---------------------------------------------------------------------------
// K3: fc MFMA partials (M=32 rows, N=512, K-chunk=1024). grid 128 = 32 mb x 4 kc.
// ---------------------------------------------------------------------------
__global__ __launch_bounds__(256) void k_fc(
        const unsigned short* __restrict__ s2b, const unsigned short* __restrict__ fragF,
        float* __restrict__ part) {
    __shared__ unsigned short lds[32768];        // 64 KB A-chunk

    int blk = blockIdx.x;
    int mb = blk >> 2, kc = blk & 3;
    int row0 = mb * 32;
    int tid = threadIdx.x, lane = tid & 63;
    int wave = __builtin_amdgcn_readfirstlane(tid >> 6);
    int col = lane & 15, grp = lane >> 4, sw = col & 7;

    #pragma unroll
    for (int it = 0; it < 16; ++it) {
        int u = it * 256 + tid;                  // 0..4095
        int pxl = u >> 7, kq = u & 127;
        bf16x8 v = ((const bf16x8*)s2b)[(size_t)(row0 + pxl) * 512 + kc * 128 + kq];
        ((bf16x8*)lds)[pxl * 128 + (kq ^ (pxl & 7))] = v;
    }
    __syncthreads();

    f32x4 acc[2][8];
    #pragma unroll
    for (int m = 0; m < 2; ++m)
        #pragma unroll
        for (int n = 0; n < 8; ++n) acc[m][n] = (f32x4)(0.f);

    const bf16x8* Af = (const bf16x8*)lds;
    const bf16x8* Bf = (const bf16x8*)fragF;
    int nt0 = wave * 8;
    #pragma unroll 4
    for (int ki = 0; ki < 32; ++ki) {
        int kk = kc * 32 + ki;
        bf16x8 a0 = Af[col * 128 + ((ki * 4 + grp) ^ sw)];
        bf16x8 a1 = Af[(16 + col) * 128 + ((ki * 4 + grp) ^ sw)];
        #pragma unroll
        for (int n = 0; n < 8; ++n) {
            bf16x8 b = Bf[((nt0 + n) * 128 + kk) * 64 + lane];
            acc[0][n] = MFMA(a0, b, acc[0][n]);
            acc[1][n] = MFMA(a1, b, acc[1][n]);
        }
    }

    float* pp = part + (size_t)kc * 524288;
    #pragma unroll
    for (int m = 0; m < 2; ++m)
        #pragma unroll
        for (int n = 0; n < 8; ++n)
            #pragma unroll
            for (int j = 0; j < 4; ++j) {
                int row = row0 + m * 16 + grp * 4 + j;
                int co = (nt0 + n) * 16 + col;
                pp[(size_t)row * 512 + co] = acc[m][n][j];
            }
}

// K3b: sum 4 K-partials + bias -> emb (fp32)
__global__ __launch_bounds__(256) void k_fc_sum(
        const float* __restrict__ part, const float* __restrict__ bias,
        float* __restrict__ emb) {
    int i = blockIdx.x * 256 + threadIdx.x;
    size_t q = (size_t)i * 4;
    float4 s0 = *(const float4*)(part + q);
    float4 s1 = *(const float4*)(part + 524288 + q);
    float4 s2 = *(const float4*)(part + 1048576 + q);
    float4 s3 = *(const float4*)(part + 1572864 + q);
    float4 bv = *(const float4*)(bias + (q & 511));
    float4 r;
    r.x = s0.x + s1.x + s2.x + s3.x + bv.x;
    r.y = s0.y + s1.y + s2.y + s3.y + bv.y;
    r.z = s0.z + s1.z + s2.z + s3.z + bv.z;
    r.w = s0.w + s1.w + s2.w + s3.w + bv.w;
    *(float4*)(emb + q) = r;
}

// ---------------------------------------------------------------------------
// K4: Fourier gating (fp32).
// ---------------------------------------------------------------------------
__global__ __launch_bounds__(256) void k_gate(
        const float* __restrict__ emb, const float* __restrict__ wg,
        float* __restrict__ topw, int* __restrict__ topi) {
    __shared__ float ct[128], st[128];
    __shared__ float red[32];

    int b = blockIdx.x, tid = threadIdx.x;
    if (tid < 128) {
        int f = tid >> 4, t = tid & 15;
        int m16 = ((f + 1) * t) & 15;
        float ang = 3.14159265358979323846f * (float)m16 * 0.125f;
        ct[tid] = cosf(ang);
        st[tid] = sinf(ang);
    }
    __syncthreads();

    float ampsum[8] = {0,0,0,0,0,0,0,0};
    #pragma unroll
    for (int dd = 0; dd < 2; ++dd) {
        int d = tid + dd * 256;
        float v[16];
        #pragma unroll
        for (int t = 0; t < 16; ++t)
            v[t] = emb[((size_t)b * 16 + t) * 512 + d];
        #pragma unroll
        for (int f = 0; f < 8; ++f) {
            float re = v[0], im = 0.f;
            #pragma unroll
            for (int t = 1; t < 16; ++t) {
                re += v[t] * ct[f * 16 + t];
                im += v[t] * st[f * 16 + t];
            }
            ampsum[f] += sqrtf(re * re + im * im);
        }
    }
    int lane = tid & 63, wave = tid >> 6;
    #pragma unroll
    for (int f = 0; f < 8; ++f) {
        float sv = ampsum[f];
        #pragma unroll
        for (int d = 1; d < 64; d <<= 1) sv += __shfl_xor(sv, d, 64);
        if (lane == 0) red[wave * 8 + f] = sv;
    }
    __syncthreads();
    if (tid == 0) {
        float wts[6];
        #pragma unroll
        for (int e = 0; e < 6; ++e) wts[e] = 0.f;
        #pragma unroll
        for (int f = 0; f < 8; ++f) {
            float S = (red[f] + red[8 + f] + red[16 + f] + red[24 + f])
                      * (0.25f / 512.0f);
            #pragma unroll
            for (int e = 0; e < 6; ++e) wts[e] += S * wg[f * 6 + e];
        }
        int i1 = 0;
        for (int e = 1; e < 6; ++e) if (wts[e] > wts[i1]) i1 = e;
        int i2 = -1;
        for (int e = 0; e < 6; ++e)
            if (e != i1 && (i2 < 0 || wts[e] > wts[i2])) i2 = e;
        float ex = expf(wts[i2] - wts[i1]);
        float den = 1.0f + ex;
        topw[b * 2] = 1.0f / den;
        topw[b * 2 + 1] = ex / den;
        topi[b * 2] = i1;
        topi[b * 2 + 1] = i2;
    }
}

// ---------------------------------------------------------------------------
// K5: routed experts MFMA (M=16, N=512, K=512, 2 experts) + exp/log combine.
// grid 64 (one block per batch b). Wave owns N-quarter (8 N-tiles) x 2 experts.
// ---------------------------------------------------------------------------
__global__ __launch_bounds__(256) void k_expert(
        const float* __restrict__ emb, const unsigned short* __restrict__ fragE,
        const float* __restrict__ eb, const float* __restrict__ topw,
        const int* __restrict__ topi, float* __restrict__ out) {
    __shared__ unsigned short lds[8192];         // 16 KB: A 16x512 bf16

    int b = blockIdx.x;
    int tid = threadIdx.x, lane = tid & 63;
    int wave = __builtin_amdgcn_readfirstlane(tid >> 6);
    int col = lane & 15, grp = lane >> 4, sw = col & 7;

    #pragma unroll
    for (int it = 0; it < 4; ++it) {
        int i = it * 256 + tid;                  // 0..1023
        int pxl = i >> 6, kq = i & 63;
        const float* p = emb + ((size_t)b * 16 + pxl) * 512 + kq * 8;
        float4 v0 = *(const float4*)p;
        float4 v1 = *(const float4*)(p + 4);
        ((bf16x8*)lds)[pxl * 64 + (kq ^ (pxl & 7))] = pack8(v0, v1);
    }
    int e1 = topi[b * 2], e2 = topi[b * 2 + 1];
    float g1 = topw[b * 2], g2 = topw[b * 2 + 1];
    __syncthreads();

    f32x4 acc[2][8];
    #pragma unroll
    for (int m = 0; m < 2; ++m)
        #pragma unroll
        for (int n = 0; n < 8; ++n) acc[m][n] = (f32x4)(0.f);

    const bf16x8* Af = (const bf16x8*)lds;
    const bf16x8* Bf = (const bf16x8*)fragE;
    int nt0 = wave * 8;
    #pragma unroll 4
    for (int ki = 0; ki < 16; ++ki) {
        bf16x8 a = Af[col * 64 + ((ki * 4 + grp) ^ sw)];
        #pragma unroll
        for (int n = 0; n < 8; ++n) {
            bf16x8 b1 = Bf[((size_t)(e1 * 512 + (nt0 + n) * 16 + ki)) * 64 + lane];
            bf16x8 b2 = Bf[((size_t)(e2 * 512 + (nt0 + n) * 16 + ki)) * 64 + lane];
            acc[0][n] = MFMA(a, b1, acc[0][n]);
            acc[1][n] = MFMA(a, b2, acc[1][n]);
        }
    }

    #pragma unroll
    for (int n = 0; n < 8; ++n) {
        int co = (nt0 + n) * 16 + col;
        float b1v = eb[e1 * 512 + co], b2v = eb[e2 * 512 + co];
        #pragma unroll
        for (int j = 0; j < 4; ++j) {
            int row = grp * 4 + j;
            float c = g1 * expf(acc[0][n][j] + b1v) + g2 * expf(acc[1][n][j] + b2v);
            if (c == 0.f) c = EPS_;
            out[((size_t)b * 16 + row) * 512 + co] = logf(c);
        }
    }
}

// ---------------------------------------------------------------------------
extern "C" void kernel_launch(void* const* d_in, const int* in_sizes, int n_in,
                              void* d_out, int out_size, void* d_ws, size_t ws_size,
                              hipStream_t stream) {
    (void)in_sizes; (void)n_in; (void)out_size; (void)ws_size;
    const float* x   = (const float*)d_in[0];
    const float* c1w = (const float*)d_in[1];
    const float* c1b = (const float*)d_in[2];
    const float* l1g = (const float*)d_in[3];
    const float* l1b = (const float*)d_in[4];
    const float* c2w = (const float*)d_in[5];
    const float* c2b = (const float*)d_in[6];
    const float* l2g = (const float*)d_in[7];
    const float* l2b = (const float*)d_in[8];
    const float* fcw = (const float*)d_in[9];
    const float* fcb = (const float*)d_in[10];
    const float* wg  = (const float*)d_in[11];
    const float* ew  = (const float*)d_in[12];
    const float* eb  = (const float*)d_in[13];
    float* out = (float*)d_out;

    unsigned short* wsu  = (unsigned short*)d_ws;
    unsigned short* frag1 = wsu;                    // 16384
    unsigned short* frag2 = frag1 + 16384;          // 262144 used (pad 524288)
    unsigned short* fragF = frag2 + 524288;         // 2097152
    unsigned short* fragE = fragF + 2097152;        // 1572864
    unsigned short* s1b   = fragE + 1572864;        // 16777216
    unsigned short* s2b   = s1b + 16777216;         // 4194304
    float* emb  = (float*)(s2b + 4194304);          // 524288 fp32
    float* part = emb + 524288;                     // 2097152 fp32
    float* topw = part + 2097152;                   // 128
    int*   topi = (int*)(topw + 128);               // 128

    hipLaunchKernelGGL(k_prep, dim3(1928), dim3(256), 0, stream,
                       c1w, c2w, fcw, ew, frag1, frag2, fragF, fragE);
    hipLaunchKernelGGL(k_conv1, dim3(2048), dim3(256), 0, stream,
                       x, frag1, c1b, l1g, l1b, s1b);
    hipLaunchKernelGGL(k_conv2, dim3(256), dim3(256), 0, stream,
                       s1b, frag2, c2b, l2g, l2b, s2b);
    hipLaunchKernelGGL(k_fc, dim3(128), dim3(256), 0, stream, s2b, fragF, part);
    hipLaunchKernelGGL(k_fc_sum, dim3(512), dim3(256), 0, stream, part, fcb, emb);
    hipLaunchKernelGGL(k_gate, dim3(64), dim3(256), 0, stream, emb, wg, topw, topi);
    hipLaunchKernelGGL(k_expert, dim3(64), dim3(256), 0, stream,
                       emb, fragE, eb, topw, topi, out);
}